// Round 1
// baseline (639.059 us; speedup 1.0000x reference)
//
#include <hip/hip_runtime.h>

// Problem constants
#define NSAMP 262144
#define CCLS 128
#define DDIM 256
#define NGB 4          // G-compute blocks in K1
#define NHEAVY 252     // argmax blocks in K1 == slots; K2 heavy = 2 chunks x 126
#define SPB 1041       // ceil(262144/252)
#define SLOT_STRIDE 1044  // 16B-aligned slot stride (elements)
#define EPSF 1e-8f

// ws byte offsets (all 16B-aligned where vector-accessed)
#define OFF_COUNTS   0u          // 128 * u32
#define OFF_LISTCNT  512u        // 252 * u32
#define OFF_G        2048u       // 128x128 f32
#define OFF_W        67584u      // 128x128 f32 (G^-1)
#define OFF_TT       133120u     // 256x128 f32 (T transposed)
#define OFF_MRAW     264192u     // 128x256 f32 (class means, unprojected)
#define OFF_B        395264u     // 128x128 f32 (Mraw @ T^T)
#define OFF_ZT       460800u     // 128x128 f32 (W @ B^T)
#define OFF_M        526336u     // 128x128 f32 (B W B^T)
#define OFF_LISTS    591872u     // 252 * 1044 * u32 -> ends 1644224
#define OFF_BIG      1644288u    // partials (252*64KB) or sums (2*64KB)
#define TOTAL_BIG    (OFF_BIG + 252u*65536u)
#define TOTAL_SMALL  (OFF_BIG + 131072u)

// ---------------------------------------------------------------------------
// K1: blocks 0..3 compute G = T*T^T (rows 32g..32g+31) + write T^T;
//     blocks 4..255: per-sample argmax over 128 logits (16-lane groups),
//     gated samples appended to a compact per-block list, per-class counts.
// ---------------------------------------------------------------------------
extern "C" __global__ __launch_bounds__(1024)
void k1_argmax_g(const float* __restrict__ logits,
                 const float* __restrict__ T,
                 const void* __restrict__ mask,
                 char* __restrict__ ws)
{
    __shared__ float Tl[64][132];          // staged T chunk, transposed, padded
    __shared__ unsigned llist[SPB];
    __shared__ int lcounts[CCLS];
    __shared__ int lcnt;
    __shared__ int sIsBool;

    const int b = blockIdx.x, tid = threadIdx.x;

    if (b < NGB) {
        // ---- G block: rows [32g, 32g+32) of G = T T^T, and T^T chunk g ----
        const int g = b;
        float* Tt = (float*)(ws + OFF_TT);
        float* G  = (float*)(ws + OFF_G);
        float a0[8], a1[8];
        #pragma unroll
        for (int j = 0; j < 8; ++j) { a0[j] = 0.f; a1[j] = 0.f; }
        const int Lr = 2 * (tid >> 4);     // local row pair (valid for tid<256)
        const int c0 = 8 * (tid & 15);     // col tile base
        for (int ch = 0; ch < 4; ++ch) {
            for (int i = tid; i < 8192; i += 1024) {
                int cc = i >> 6, dd = i & 63;
                Tl[dd][cc] = T[cc * 256 + ch * 64 + dd];
            }
            __syncthreads();
            if (g == ch) { // write T^T rows [64ch, 64ch+64)
                for (int i = tid; i < 8192; i += 1024) {
                    int c2 = i & 127, d2 = i >> 7;
                    Tt[(ch * 64 + d2) * 128 + c2] = Tl[d2][c2];
                }
            }
            if (tid < 256) {
                for (int dd = 0; dd < 64; ++dd) {
                    float r0 = Tl[dd][32 * g + Lr];
                    float r1 = Tl[dd][32 * g + Lr + 1];
                    float cv[8];
                    *(float4*)&cv[0] = *(const float4*)&Tl[dd][c0];
                    *(float4*)&cv[4] = *(const float4*)&Tl[dd][c0 + 4];
                    #pragma unroll
                    for (int j = 0; j < 8; ++j) { a0[j] += r0 * cv[j]; a1[j] += r1 * cv[j]; }
                }
            }
            __syncthreads();
        }
        if (tid < 256) {
            int gr = 32 * g + Lr;
            *(float4*)&G[gr * 128 + c0]           = make_float4(a0[0], a0[1], a0[2], a0[3]);
            *(float4*)&G[gr * 128 + c0 + 4]       = make_float4(a0[4], a0[5], a0[6], a0[7]);
            *(float4*)&G[(gr + 1) * 128 + c0]     = make_float4(a1[0], a1[1], a1[2], a1[3]);
            *(float4*)&G[(gr + 1) * 128 + c0 + 4] = make_float4(a1[4], a1[5], a1[6], a1[7]);
        }
        return;
    }

    // ---- argmax block ----
    const int hb = b - NGB;
    unsigned* gLists = (unsigned*)(ws + OFF_LISTS);
    int* gListCnt = (int*)(ws + OFF_LISTCNT);
    int* gCounts  = (int*)(ws + OFF_COUNTS);

    { // gate_mask dtype auto-detect: byte-packed bool reinterpreted as i32 gives values >1
        int v = 0;
        if (tid < 64) v = ((const int*)mask)[tid];
        unsigned long long bal = __ballot((unsigned)v > 1u);
        if (tid == 0) { sIsBool = (bal != 0ull); lcnt = 0; }
        for (int i = tid; i < CCLS; i += 1024) lcounts[i] = 0;
    }
    __syncthreads();
    const bool isBool = (sIsBool != 0);

    const int start = hb * SPB;
    const int end = min(NSAMP, start + SPB);
    const int gid = tid >> 4, li = tid & 15;

    for (int s = start + gid; s < end; s += 64) {
        const float4* lp = (const float4*)(logits + (size_t)s * CCLS);
        float4 x = lp[li], y = lp[li + 16];
        float m = x.x; int id = 4 * li;
        if (x.y > m) { m = x.y; id = 4 * li + 1; }
        if (x.z > m) { m = x.z; id = 4 * li + 2; }
        if (x.w > m) { m = x.w; id = 4 * li + 3; }
        if (y.x > m) { m = y.x; id = 64 + 4 * li; }
        if (y.y > m) { m = y.y; id = 64 + 4 * li + 1; }
        if (y.z > m) { m = y.z; id = 64 + 4 * li + 2; }
        if (y.w > m) { m = y.w; id = 64 + 4 * li + 3; }
        #pragma unroll
        for (int off = 8; off > 0; off >>= 1) {
            float om = __shfl_down(m, off, 16);
            int   oi = __shfl_down(id, off, 16);
            if (om > m || (om == m && oi < id)) { m = om; id = oi; }
        }
        if (li == 0) {
            int gv = isBool ? (int)((const unsigned char*)mask)[s] : ((const int*)mask)[s];
            if (gv) {
                int pos = atomicAdd(&lcnt, 1);
                llist[pos] = ((unsigned)id << 18) | (unsigned)s;
                atomicAdd(&lcounts[id], 1);
            }
        }
    }
    __syncthreads();
    const int n = lcnt;
    for (int i = tid; i < n; i += 1024) gLists[hb * SLOT_STRIDE + i] = llist[i];
    if (tid == 0) gListCnt[hb] = n;
    if (tid < CCLS && lcounts[tid]) atomicAdd(&gCounts[tid], lcounts[tid]);
}

// ---------------------------------------------------------------------------
// K2: block 0: in-place Gauss-Jordan inversion of G (SPD, no pivoting) -> W.
//     blocks 1..252: gated segment-sum of img_feats, LDS-privatized
//     (128 classes x 128-dim chunk, even/odd dim permutation so ds_add is
//     conflict-free), flushed to ws partials (or f32 atomics fallback).
// ---------------------------------------------------------------------------
extern "C" __global__ __launch_bounds__(1024)
void k2_segsum_inv(const float* __restrict__ img, char* __restrict__ ws, int usePartials)
{
    __shared__ float acc[CCLS][CCLS];     // 64KB; block 0 aliases rows 0..3 as buffers
    const int b = blockIdx.x, tid = threadIdx.x;

    if (b == 0) {
        const float* G = (const float*)(ws + OFF_G);
        float* W = (float*)(ws + OFF_W);
        float* prowA = acc[0]; float* prowB = acc[1];
        float* pcolA = acc[2]; float* pcolB = acc[3];
        float gg[8][8];
        const int r0 = 8 * (tid >> 4), c0 = 8 * (tid & 15);
        if (tid < 256) {
            #pragma unroll
            for (int ii = 0; ii < 8; ++ii) {
                *(float4*)&gg[ii][0] = *(const float4*)&G[(r0 + ii) * 128 + c0];
                *(float4*)&gg[ii][4] = *(const float4*)&G[(r0 + ii) * 128 + c0 + 4];
            }
            if (r0 == 0) {
                #pragma unroll
                for (int j = 0; j < 8; ++j) prowA[c0 + j] = gg[0][j];
            }
            if (c0 == 0) {
                #pragma unroll
                for (int i = 0; i < 8; ++i) pcolA[r0 + i] = gg[i][0];
            }
        }
        __syncthreads();
        for (int k = 0; k < 128; ++k) {
            if (tid < 256) {
                const float* pr = (k & 1) ? prowB : prowA;
                const float* pc = (k & 1) ? pcolB : pcolA;
                float rinv = 1.0f / pr[k];
                float rf[8], fc[8];
                #pragma unroll
                for (int j = 0; j < 8; ++j) { rf[j] = pr[c0 + j] * rinv; if (c0 + j == k) rf[j] = rinv; }
                #pragma unroll
                for (int i = 0; i < 8; ++i) fc[i] = pc[r0 + i];
                #pragma unroll
                for (int i = 0; i < 8; ++i) {
                    if (r0 + i == k) {
                        #pragma unroll
                        for (int j = 0; j < 8; ++j) gg[i][j] = rf[j];
                    } else {
                        float f = fc[i];
                        #pragma unroll
                        for (int j = 0; j < 8; ++j) {
                            float base = (c0 + j == k) ? 0.0f : gg[i][j];
                            gg[i][j] = base - f * rf[j];
                        }
                    }
                }
                int kn = k + 1;
                if (kn < 128) {
                    float* prn = (kn & 1) ? prowB : prowA;
                    float* pcn = (kn & 1) ? pcolB : pcolA;
                    if (kn >= r0 && kn < r0 + 8) {
                        #pragma unroll
                        for (int j = 0; j < 8; ++j) prn[c0 + j] = gg[kn - r0][j];
                    }
                    if (kn >= c0 && kn < c0 + 8) {
                        #pragma unroll
                        for (int i = 0; i < 8; ++i) pcn[r0 + i] = gg[i][kn - c0];
                    }
                }
            }
            __syncthreads();
        }
        if (tid < 256) {
            #pragma unroll
            for (int ii = 0; ii < 8; ++ii) {
                *(float4*)&W[(r0 + ii) * 128 + c0]     = *(float4*)&gg[ii][0];
                *(float4*)&W[(r0 + ii) * 128 + c0 + 4] = *(float4*)&gg[ii][4];
            }
        }
        return;
    }

    // ---- heavy segment-sum block ----
    const int idx = b - 1;
    const int chunk = idx / 126, hb2 = idx % 126;
    const unsigned* gLists = (const unsigned*)(ws + OFF_LISTS);
    const int* gListCnt = (const int*)(ws + OFF_LISTCNT);
    float* accF = &acc[0][0];
    for (int i = tid; i < 16384; i += 1024) accF[i] = 0.f;
    __syncthreads();

    const int wid = tid >> 6, lane = tid & 63;
    const float2* img2 = (const float2*)img;
    for (int sl = 0; sl < 2; ++sl) {
        const int slot = 2 * hb2 + sl;
        const int cnt = gListCnt[slot];
        const uint4* ep = (const uint4*)(gLists + slot * SLOT_STRIDE);
        for (int i = wid * 4; i < cnt; i += 64) {
            uint4 e4 = ep[i >> 2];
            #pragma unroll
            for (int u = 0; u < 4; ++u) {
                if (i + u < cnt) {
                    unsigned e = (&e4.x)[u];
                    int s = e & 0x3FFFF, c = (int)(e >> 18);
                    float2 v = img2[(size_t)s * 128 + chunk * 64 + lane];
                    atomicAdd(&acc[c][lane], v.x);        // even dim -> slot lane
                    atomicAdd(&acc[c][64 + lane], v.y);   // odd dim  -> slot 64+lane
                }
            }
        }
    }
    __syncthreads();
    if (usePartials) {
        float* pp = (float*)(ws + OFF_BIG) + (size_t)idx * 16384;
        for (int i = tid; i < 16384; i += 1024) pp[i] = accF[i];
    } else {
        float* sums = (float*)(ws + OFF_BIG);
        for (int i = tid; i < 16384; i += 1024)
            if (accF[i] != 0.f) unsafeAtomicAdd(&sums[chunk * 16384 + i], accF[i]);
    }
}

// ---------------------------------------------------------------------------
// K3: reduce partials -> class means Mraw (un-permuting even/odd dim layout)
// ---------------------------------------------------------------------------
extern "C" __global__ __launch_bounds__(128)
void k3_means(char* __restrict__ ws, int usePartials)
{
    const int chunk = blockIdx.x >> 7, c = blockIdx.x & 127, slot = threadIdx.x;
    float a = 0.f;
    if (usePartials) {
        const float* base = (const float*)(ws + OFF_BIG) + (size_t)(chunk * 126) * 16384 + c * 128 + slot;
        for (int rb = 0; rb < 126; ++rb) a += base[(size_t)rb * 16384];
    } else {
        a = ((const float*)(ws + OFF_BIG))[chunk * 16384 + c * 128 + slot];
    }
    const int* counts = (const int*)(ws + OFF_COUNTS);
    int dt = chunk * 128 + (slot < 64 ? 2 * slot : 2 * (slot - 64) + 1);
    float cf = fmaxf((float)counts[c], 1.0f);
    ((float*)(ws + OFF_MRAW))[c * 256 + dt] = a / cf;
}

// K4: B = Mraw @ T^T  (128x128)
extern "C" __global__ __launch_bounds__(128)
void k4_B(char* __restrict__ ws)
{
    __shared__ float mr[256];
    const int c = blockIdx.x, j = threadIdx.x;
    const float* Mraw = (const float*)(ws + OFF_MRAW);
    const float* Tt = (const float*)(ws + OFF_TT);
    mr[j] = Mraw[c * 256 + j]; mr[j + 128] = Mraw[c * 256 + 128 + j];
    __syncthreads();
    float a = 0.f;
    #pragma unroll 8
    for (int d = 0; d < 256; ++d) a += mr[d] * Tt[d * 128 + j];
    ((float*)(ws + OFF_B))[c * 128 + j] = a;
}

// K5: Zt = (B @ W)^T = W @ B^T   (W symmetric)
extern "C" __global__ __launch_bounds__(128)
void k5_Z(char* __restrict__ ws)
{
    __shared__ float bc[128];
    const int c = blockIdx.x, j = threadIdx.x;
    const float* B = (const float*)(ws + OFF_B);
    const float* W = (const float*)(ws + OFF_W);
    bc[j] = B[c * 128 + j];
    __syncthreads();
    float a = 0.f;
    #pragma unroll 8
    for (int k = 0; k < 128; ++k) a += bc[k] * W[k * 128 + j];
    ((float*)(ws + OFF_ZT))[j * 128 + c] = a;
}

// K6: M = B @ Zt = B W B^T  (Gram matrix of projected class means)
extern "C" __global__ __launch_bounds__(128)
void k6_M(char* __restrict__ ws)
{
    __shared__ float bc[128];
    const int c = blockIdx.x, j = threadIdx.x;
    const float* B = (const float*)(ws + OFF_B);
    const float* Zt = (const float*)(ws + OFF_ZT);
    bc[j] = B[c * 128 + j];
    __syncthreads();
    float a = 0.f;
    #pragma unroll 8
    for (int k = 0; k < 128; ++k) a += bc[k] * Zt[k * 128 + j];
    ((float*)(ws + OFF_M))[c * 128 + j] = a;
}

// K7: loss = sum over present pairs c!=j of 1 - M[c][j]/((sqrt(Mcc)+eps)(sqrt(Mjj)+eps))
extern "C" __global__ __launch_bounds__(256)
void k7_loss(char* __restrict__ ws, float* __restrict__ out)
{
    __shared__ float norms[128];
    __shared__ int pres[128];
    __shared__ float wsum[4];
    const int tid = threadIdx.x;
    const float* M = (const float*)(ws + OFF_M);
    const int* counts = (const int*)(ws + OFF_COUNTS);
    if (tid < 128) {
        int p = counts[tid] > 0;
        pres[tid] = p;
        norms[tid] = sqrtf(p ? M[tid * 129] : 1.0f);
    }
    __syncthreads();
    float ls = 0.f;
    for (int idx = tid; idx < 16384; idx += 256) {
        int c = idx >> 7, j = idx & 127;
        if (c != j && pres[c] && pres[j])
            ls += 1.0f - M[idx] / ((norms[c] + EPSF) * (norms[j] + EPSF));
    }
    #pragma unroll
    for (int off = 32; off > 0; off >>= 1) ls += __shfl_down(ls, off);
    if ((tid & 63) == 0) wsum[tid >> 6] = ls;
    __syncthreads();
    if (tid == 0) {
        int np = 0;
        for (int c = 0; c < 128; ++c) np += pres[c];
        float tot = wsum[0] + wsum[1] + wsum[2] + wsum[3];
        out[0] = (np >= 2) ? tot : 0.0f;
    }
}

// ---------------------------------------------------------------------------
extern "C" void kernel_launch(void* const* d_in, const int* in_sizes, int n_in,
                              void* d_out, int out_size, void* d_ws, size_t ws_size,
                              hipStream_t stream)
{
    const float* logits = (const float*)d_in[0];
    const float* img    = (const float*)d_in[1];
    const float* T      = (const float*)d_in[2];
    const void*  mask   = d_in[3];
    char* ws = (char*)d_ws;

    int usePartials = (ws_size >= (size_t)TOTAL_BIG) ? 1 : 0;

    hipMemsetAsync(ws + OFF_COUNTS, 0, 512, stream);
    if (!usePartials) hipMemsetAsync(ws + OFF_BIG, 0, 131072, stream);

    k1_argmax_g<<<NGB + NHEAVY, 1024, 0, stream>>>(logits, T, mask, ws);
    k2_segsum_inv<<<1 + 2 * 126, 1024, 0, stream>>>(img, ws, usePartials);
    k3_means<<<256, 128, 0, stream>>>(ws, usePartials);
    k4_B<<<128, 128, 0, stream>>>(ws);
    k5_Z<<<128, 128, 0, stream>>>(ws);
    k6_M<<<128, 128, 0, stream>>>(ws);
    k7_loss<<<1, 256, 0, stream>>>(ws, (float*)d_out);
}